// Round 3
// baseline (2163.119 us; speedup 1.0000x reference)
//
#include <hip/hip_runtime.h>
#include <math.h>

// ---------------------------------------------------------------------------
// RefEncoder: 4x stride-2 conv encoder (fp32, LDS-staged direct conv) + VQ head
// Block = 256 threads (16x16 pixel grid), each thread COPT chans x PY*PX pix.
// Per ci-chunk barrier round: block cooperatively stages the input window
// (2*TH+1 x 2*TW+1, row stride padded to x4 for ds_read_b128) and the chunk's
// weights into LDS with coalesced loads; compute then reads windows from LDS.
// Output (int32): 16384 codes [n,hh,ww,m] + tail [256,256]
// ---------------------------------------------------------------------------

__device__ __forceinline__ float gelu_tanh(float x) {
    float x3 = x * x * x;
    return 0.5f * x * (1.0f + tanhf(0.7978845608028654f * (x + 0.044715f * x3)));
}

template <int Ci, int Co, int Hi, int Wi, int COPT, int PY, int PX, int CC,
          bool DO_GELU, bool NORM_IN>
__launch_bounds__(256)
__global__ void conv_lds_kernel(const float* __restrict__ in,
                                const float* __restrict__ w,
                                const float* __restrict__ bias,
                                float* __restrict__ out, int N) {
    constexpr int Ho = Hi / 2, Wo = Wi / 2;
    constexpr int TH = 16 * PY, TW = 16 * PX;          // block output tile
    constexpr int tilesX = Wo / TW, tilesY = Ho / TH;
    constexpr int CGc = Co / COPT;
    constexpr int IHT = 2 * TH + 1, IWT = 2 * TW + 1;  // staged input window
    constexpr int ISTR = (IWT + 3) & ~3;               // 16B-aligned row stride
    constexpr int IH = 2 * PY + 1, IW = 2 * PX + 1;    // per-thread window
    constexpr int WCHUNK = CC * 9 * COPT;

    __shared__ float lds_in[CC][IHT][ISTR];
    __shared__ float lds_w[WCHUNK];

    int t = threadIdx.x;
    int tx = t & 15, ty = t >> 4;
    int bx = blockIdx.x;
    int tileX = bx % tilesX; bx /= tilesX;
    int tileY = bx % tilesY; bx /= tilesY;
    int cg = bx % CGc;
    int n = bx / CGc;
    const int co0 = cg * COPT;
    const int iy0 = tileY * TH * 2;                    // window origin in input
    const int ix0 = tileX * TW * 2;

    float acc[COPT][PY * PX];
#pragma unroll
    for (int j = 0; j < COPT; ++j)
#pragma unroll
        for (int p = 0; p < PY * PX; ++p) acc[j][p] = 0.0f;

    for (int ci0 = 0; ci0 < Ci; ci0 += CC) {
        __syncthreads();
        // stage input window(s), coalesced along rows; pad cols/rows -> 0
        for (int e = t; e < CC * IHT * ISTR; e += 256) {
            int c = e % ISTR;
            int r = (e / ISTR) % IHT;
            int cl = e / (ISTR * IHT);
            int iy = iy0 + r, ix = ix0 + c;
            float val = 0.0f;
            if (c < IWT && iy < Hi && ix < Wi) {
                val = in[((size_t)(n * Ci + ci0 + cl) * Hi + iy) * Wi + ix];
                if (NORM_IN) val = 2.0f * val - 1.0f;  // pad stays 0
            }
            lds_in[cl][r][c] = val;
        }
        // stage weights [cl][tap][j]
        for (int e = t; e < WCHUNK; e += 256) {
            int j = e % COPT;
            int tap = (e / COPT) % 9;
            int cl = e / (COPT * 9);
            lds_w[e] = w[((size_t)(co0 + j) * Ci + ci0 + cl) * 9 + tap];
        }
        __syncthreads();

#pragma unroll
        for (int cl = 0; cl < CC; ++cl) {
            float v[IH][IW];
#pragma unroll
            for (int dy = 0; dy < IH; ++dy)
#pragma unroll
                for (int dx = 0; dx < IW; ++dx)
                    v[dy][dx] = lds_in[cl][2 * ty * PY + dy][2 * tx * PX + dx];
            const float* wp = lds_w + cl * 9 * COPT;
#pragma unroll
            for (int ky = 0; ky < 3; ++ky)
#pragma unroll
                for (int kx = 0; kx < 3; ++kx) {
                    const float* wt = wp + (ky * 3 + kx) * COPT;
#pragma unroll
                    for (int j = 0; j < COPT; ++j) {
                        float wj = wt[j];
#pragma unroll
                        for (int py = 0; py < PY; ++py)
#pragma unroll
                            for (int px = 0; px < PX; ++px)
                                acc[j][py * PX + px] +=
                                    v[2 * py + ky][2 * px + kx] * wj;
                    }
                }
        }
    }

#pragma unroll
    for (int j = 0; j < COPT; ++j) {
        float bj = bias[co0 + j];
#pragma unroll
        for (int py = 0; py < PY; ++py) {
            int oy = tileY * TH + ty * PY + py;
#pragma unroll
            for (int px = 0; px < PX; ++px) {
                int ox = tileX * TW + tx * PX + px;
                float r = acc[j][py * PX + px] + bj;
                if (DO_GELU) r = gelu_tanh(r);
                out[(((size_t)n * Co + co0 + j) * Ho + oy) * Wo + ox] = r;
            }
        }
    }
}

// kproj[m][k][c] = sum_d codebook[m][k][d] * wk[m][c][d]
__global__ void kproj_kernel(const float* __restrict__ cb,
                             const float* __restrict__ wk,
                             float* __restrict__ kp) {
    int m = blockIdx.x >> 8;
    int k = blockIdx.x & 255;
    int c = threadIdx.x;
    const float* cbp = cb + (size_t)(m * 256 + k) * 64;
    const float* wkp = wk + (size_t)(m * 64 + c) * 64;
    float acc = 0.0f;
#pragma unroll 8
    for (int d = 0; d < 64; ++d) acc += cbp[d] * wkp[d];
    kp[(size_t)(m * 256 + k) * 64 + c] = acc;
}

// One block (256 threads) per latent pixel (n,hh,ww). Wave m handles group m.
__global__ void head_kernel(const float* __restrict__ latent,
                            const float* __restrict__ wq,
                            const float* __restrict__ kp,
                            int* __restrict__ out) {
    __shared__ float lat[256];
    __shared__ float q[256];
    int t = threadIdx.x;
    int pix = blockIdx.x;
    int wx = pix & 15, hh = (pix >> 4) & 15, n = pix >> 8;

    lat[t] = latent[(((size_t)n * 256 + t) * 16 + hh) * 16 + wx];
    __syncthreads();

    int m = t >> 6, c = t & 63;
    const float* wqp = wq + (size_t)(m * 64 + c) * 64;
    float acc = 0.0f;
#pragma unroll 8
    for (int d = 0; d < 64; ++d) acc += lat[m * 64 + d] * wqp[d];
    q[t] = acc;
    __syncthreads();

    float best = -INFINITY;
    int bestk = 0;
    for (int j = 0; j < 4; ++j) {
        int k = j * 64 + c;
        const float* kpp = kp + (size_t)(m * 256 + k) * 64;
        float s = 0.0f;
#pragma unroll 8
        for (int d = 0; d < 64; ++d) s += q[m * 64 + d] * kpp[d];
        if (s > best) { best = s; bestk = k; }
    }
    for (int off = 32; off > 0; off >>= 1) {
        float s2 = __shfl_down(best, off, 64);
        int   k2 = __shfl_down(bestk, off, 64);
        if (s2 > best || (s2 == best && k2 < bestk)) { best = s2; bestk = k2; }
    }
    if (c == 0) out[pix * 4 + m] = bestk;
    if (pix == 0 && t == 0) { out[16384] = 256; out[16385] = 256; }
}

extern "C" void kernel_launch(void* const* d_in, const int* in_sizes, int n_in,
                              void* d_out, int out_size, void* d_ws, size_t ws_size,
                              hipStream_t stream) {
    const float* x  = (const float*)d_in[0];
    const float* w1 = (const float*)d_in[1];  const float* b1 = (const float*)d_in[2];
    const float* w2 = (const float*)d_in[3];  const float* b2 = (const float*)d_in[4];
    const float* w3 = (const float*)d_in[5];  const float* b3 = (const float*)d_in[6];
    const float* w4 = (const float*)d_in[7];  const float* b4 = (const float*)d_in[8];
    const float* cb = (const float*)d_in[9];
    const float* wq = (const float*)d_in[10];
    const float* wk = (const float*)d_in[11];
    int* out = (int*)d_out;

    const int N = 16;
    float* buf1 = (float*)d_ws;                               // 16*64*128*128
    float* buf2 = buf1 + (size_t)16 * 64 * 128 * 128;         // 16*128*64*64
    float* buf3 = buf2 + (size_t)16 * 128 * 64 * 64;          // 16*256*32*32
    float* buf4 = buf3 + (size_t)16 * 256 * 32 * 32;          // 16*256*16*16
    float* kp   = buf4 + (size_t)16 * 256 * 16 * 16;          // 4*256*64

    // conv1: 3->64, tile 32x32, COPT=8, CC=1 (LDS 17.7KB)
    {
        int grid = N * (64 / 8) * (128 / 32) * (128 / 32);    // 2048
        conv_lds_kernel<3, 64, 256, 256, 8, 2, 2, 1, true, true>
            <<<grid, 256, 0, stream>>>(x, w1, b1, buf1, N);
    }
    // conv2: 64->128, tile 32x32, COPT=8, CC=1
    {
        int grid = N * (128 / 8) * (64 / 32) * (64 / 32);     // 1024
        conv_lds_kernel<64, 128, 128, 128, 8, 2, 2, 1, true, false>
            <<<grid, 256, 0, stream>>>(buf1, w2, b2, buf2, N);
    }
    // conv3: 128->256, tile 32x32 (whole plane), COPT=8, CC=1
    {
        int grid = N * (256 / 8);                             // 512
        conv_lds_kernel<128, 256, 64, 64, 8, 2, 2, 1, true, false>
            <<<grid, 256, 0, stream>>>(buf2, w3, b3, buf3, N);
    }
    // conv4: 256->256, tile 16x16 (whole plane), COPT=8, PY=PX=1, CC=4 (19KB)
    {
        int grid = N * (256 / 8);                             // 512
        conv_lds_kernel<256, 256, 32, 32, 8, 1, 1, 4, false, false>
            <<<grid, 256, 0, stream>>>(buf3, w4, b4, buf4, N);
    }
    kproj_kernel<<<4 * 256, 64, 0, stream>>>(cb, wk, kp);
    head_kernel<<<16 * 16 * 16, 256, 0, stream>>>(buf4, wq, kp, out);
}

// Round 4
// 1519.800 us; speedup vs baseline: 1.4233x; 1.4233x over previous
//
#include <hip/hip_runtime.h>
#include <math.h>

// ---------------------------------------------------------------------------
// RefEncoder: 4x stride-2 conv encoder (fp32) + VQ head.
// Conv structure (per block = 256 threads = 16x16 pixel grid, PY=1):
//   - input window (2*TH+1 x 2*TW+1, row stride padded to x4) staged in LDS
//     with coalesced loads; per-thread (row,col,valid) staging descriptors
//     precomputed in registers (div/mod hoisted out of the K loop)
//   - window read back as float4 (start banks stride 4 -> conflict-free b128)
//   - weights read directly from global with wave-uniform addresses -> s_load
//     (scalar pipe; NEVER through LDS - LDS is shared by 4 SIMDs/CU)
//   - acc[COPT][PX] in VGPRs; contiguous float2 stores
// Output (int32): 16384 codes [n,hh,ww,m] + tail [256,256]
// ---------------------------------------------------------------------------

__device__ __forceinline__ float gelu_tanh(float x) {
    float x3 = x * x * x;
    return 0.5f * x * (1.0f + tanhf(0.7978845608028654f * (x + 0.044715f * x3)));
}

template <int Ci, int Co, int Hi, int Wi, int COPT, int PX, int CC,
          bool DO_GELU, bool NORM_IN>
__launch_bounds__(256)
__global__ void conv_k(const float* __restrict__ in, const float* __restrict__ w,
                       const float* __restrict__ bias, float* __restrict__ out) {
    constexpr int Ho = Hi / 2, Wo = Wi / 2;
    constexpr int TH = 16, TW = 16 * PX;
    constexpr int tilesX = Wo / TW, tilesY = Ho / TH, CG = Co / COPT;
    constexpr int IHT = 2 * TH + 1, IWT = 2 * TW + 1;
    constexpr int ISTR = (IWT + 3) & ~3;           // 16B-aligned row stride
    constexpr int NELEM = CC * IHT * ISTR;
    constexpr int NLD = (NELEM + 255) / 256;
    constexpr int IW = 2 * PX + 1;

    __shared__ float lds[NELEM];

    const int t = threadIdx.x;
    const int tx = t & 15, ty = t >> 4;
    int bx = blockIdx.x;
    const int tileX = bx % tilesX; bx /= tilesX;
    const int tileY = bx % tilesY; bx /= tilesY;
    const int cg = bx % CG;
    const int n = bx / CG;
    const int co0 = cg * COPT;
    const int iy0 = tileY * TH * 2, ix0 = tileX * TW * 2;

    // precompute staging descriptors (round-invariant)
    int goff[NLD];
    bool ok[NLD];
#pragma unroll
    for (int i = 0; i < NLD; ++i) {
        int e = t + 256 * i;
        int cl = e / (IHT * ISTR);
        int rem = e % (IHT * ISTR);
        int r = rem / ISTR, c = rem % ISTR;
        int iy = iy0 + r, ix = ix0 + c;
        ok[i] = (e < NELEM) && (c < IWT) && (iy < Hi) && (ix < Wi);
        goff[i] = ok[i] ? (cl * Hi + iy) * Wi + ix : 0;
    }

    float acc[COPT][PX];
#pragma unroll
    for (int j = 0; j < COPT; ++j)
#pragma unroll
        for (int p = 0; p < PX; ++p) acc[j][p] = 0.0f;

    const float* inbase = in + (size_t)n * Ci * Hi * Wi;

    for (int ci0 = 0; ci0 < Ci; ci0 += CC) {
        __syncthreads();
#pragma unroll
        for (int i = 0; i < NLD; ++i) {
            int e = t + 256 * i;
            if (e < NELEM) {
                float v = 0.0f;
                if (ok[i]) {
                    v = inbase[goff[i]];
                    if (NORM_IN) v = 2.0f * v - 1.0f;  // pad stays 0
                }
                lds[e] = v;
            }
        }
        inbase += (size_t)CC * Hi * Wi;
        __syncthreads();

#pragma unroll
        for (int cl = 0; cl < CC; ++cl) {
            float win[3][IW];
#pragma unroll
            for (int dy = 0; dy < 3; ++dy) {
                const float* rowp =
                    &lds[(cl * IHT + 2 * ty + dy) * ISTR + 2 * PX * tx];
                if (PX == 2) {
                    float4 v4 = *(const float4*)rowp;
                    win[dy][0] = v4.x; win[dy][1] = v4.y;
                    win[dy][2] = v4.z; win[dy][3] = v4.w;
                    win[dy][4] = rowp[4];
                } else {
                    float2 v2 = *(const float2*)rowp;
                    win[dy][0] = v2.x; win[dy][1] = v2.y;
                    win[dy][2] = rowp[2];
                }
            }
            // weights: wave-uniform address -> scalar loads, no LDS traffic
            const float* wbase = w + ((size_t)co0 * Ci + (ci0 + cl)) * 9;
#pragma unroll
            for (int j = 0; j < COPT; ++j) {
                const float* wj = wbase + (size_t)j * Ci * 9;
#pragma unroll
                for (int ky = 0; ky < 3; ++ky)
#pragma unroll
                    for (int kx = 0; kx < 3; ++kx) {
                        float wv = wj[ky * 3 + kx];
#pragma unroll
                        for (int px = 0; px < PX; ++px)
                            acc[j][px] += win[ky][2 * px + kx] * wv;
                    }
            }
        }
    }

    const int oy = tileY * TH + ty;
    const int ox = tileX * TW + tx * PX;
#pragma unroll
    for (int j = 0; j < COPT; ++j) {
        float bj = bias[co0 + j];
        float* op = &out[(((size_t)n * Co + co0 + j) * Ho + oy) * Wo + ox];
        if (PX == 2) {
            float r0 = acc[j][0] + bj, r1 = acc[j][1] + bj;
            if (DO_GELU) { r0 = gelu_tanh(r0); r1 = gelu_tanh(r1); }
            float2 st = {r0, r1};
            *(float2*)op = st;
        } else {
            float r0 = acc[j][0] + bj;
            if (DO_GELU) r0 = gelu_tanh(r0);
            *op = r0;
        }
    }
}

// kproj[m][k][c] = sum_d codebook[m][k][d] * wk[m][c][d]
__global__ void kproj_kernel(const float* __restrict__ cb,
                             const float* __restrict__ wk,
                             float* __restrict__ kp) {
    int m = blockIdx.x >> 8;
    int k = blockIdx.x & 255;
    int c = threadIdx.x;
    const float* cbp = cb + (size_t)(m * 256 + k) * 64;
    const float* wkp = wk + (size_t)(m * 64 + c) * 64;
    float acc = 0.0f;
#pragma unroll 8
    for (int d = 0; d < 64; ++d) acc += cbp[d] * wkp[d];
    kp[(size_t)(m * 256 + k) * 64 + c] = acc;
}

// One block (256 threads) per latent pixel (n,hh,ww). Wave m handles group m.
__global__ void head_kernel(const float* __restrict__ latent,
                            const float* __restrict__ wq,
                            const float* __restrict__ kp,
                            int* __restrict__ out) {
    __shared__ float lat[256];
    __shared__ float q[256];
    int t = threadIdx.x;
    int pix = blockIdx.x;
    int wx = pix & 15, hh = (pix >> 4) & 15, n = pix >> 8;

    lat[t] = latent[(((size_t)n * 256 + t) * 16 + hh) * 16 + wx];
    __syncthreads();

    int m = t >> 6, c = t & 63;
    const float* wqp = wq + (size_t)(m * 64 + c) * 64;
    float acc = 0.0f;
#pragma unroll 8
    for (int d = 0; d < 64; ++d) acc += lat[m * 64 + d] * wqp[d];
    q[t] = acc;
    __syncthreads();

    float best = -INFINITY;
    int bestk = 0;
    for (int j = 0; j < 4; ++j) {
        int k = j * 64 + c;
        const float* kpp = kp + (size_t)(m * 256 + k) * 64;
        float s = 0.0f;
#pragma unroll 8
        for (int d = 0; d < 64; ++d) s += q[m * 64 + d] * kpp[d];
        if (s > best) { best = s; bestk = k; }
    }
    for (int off = 32; off > 0; off >>= 1) {
        float s2 = __shfl_down(best, off, 64);
        int   k2 = __shfl_down(bestk, off, 64);
        if (s2 > best || (s2 == best && k2 < bestk)) { best = s2; bestk = k2; }
    }
    if (c == 0) out[pix * 4 + m] = bestk;
    if (pix == 0 && t == 0) { out[16384] = 256; out[16385] = 256; }
}

extern "C" void kernel_launch(void* const* d_in, const int* in_sizes, int n_in,
                              void* d_out, int out_size, void* d_ws, size_t ws_size,
                              hipStream_t stream) {
    const float* x  = (const float*)d_in[0];
    const float* w1 = (const float*)d_in[1];  const float* b1 = (const float*)d_in[2];
    const float* w2 = (const float*)d_in[3];  const float* b2 = (const float*)d_in[4];
    const float* w3 = (const float*)d_in[5];  const float* b3 = (const float*)d_in[6];
    const float* w4 = (const float*)d_in[7];  const float* b4 = (const float*)d_in[8];
    const float* cb = (const float*)d_in[9];
    const float* wq = (const float*)d_in[10];
    const float* wk = (const float*)d_in[11];
    int* out = (int*)d_out;

    const int N = 16;
    float* buf1 = (float*)d_ws;                               // 16*64*128*128
    float* buf2 = buf1 + (size_t)16 * 64 * 128 * 128;         // 16*128*64*64
    float* buf3 = buf2 + (size_t)16 * 128 * 64 * 64;          // 16*256*32*32
    float* buf4 = buf3 + (size_t)16 * 256 * 32 * 32;          // 16*256*16*16
    float* kp   = buf4 + (size_t)16 * 256 * 16 * 16;          // 4*256*64

    // conv1: 3->64, COPT=8, PX=2, CC=3 (one staging round), LDS 26.9KB
    // grid = 16 * 8 * 8 * 4 = 4096
    conv_k<3, 64, 256, 256, 8, 2, 3, true, true>
        <<<16 * (64 / 8) * (128 / 16) * (128 / 32), 256, 0, stream>>>(x, w1, b1, buf1);

    // conv2: 64->128, COPT=16, PX=2, CC=2, LDS 17.9KB, grid 1024
    conv_k<64, 128, 128, 128, 16, 2, 2, true, false>
        <<<16 * (128 / 16) * (64 / 16) * (64 / 32), 256, 0, stream>>>(buf1, w2, b2, buf2);

    // conv3: 128->256, COPT=16, PX=2, CC=2, LDS 17.9KB, grid 512
    conv_k<128, 256, 64, 64, 16, 2, 2, true, false>
        <<<16 * (256 / 16) * (32 / 16) * (32 / 32), 256, 0, stream>>>(buf2, w3, b3, buf3);

    // conv4: 256->256, COPT=8, PX=1, CC=4, LDS 19KB, grid 512 (2 blocks/CU)
    conv_k<256, 256, 32, 32, 8, 1, 4, false, false>
        <<<16 * (256 / 8) * (16 / 16) * (16 / 16), 256, 0, stream>>>(buf3, w4, b4, buf4);

    kproj_kernel<<<4 * 256, 64, 0, stream>>>(cb, wk, kp);
    head_kernel<<<16 * 16 * 16, 256, 0, stream>>>(buf4, wq, kp, out);
}

// Round 5
// 1262.766 us; speedup vs baseline: 1.7130x; 1.2035x over previous
//
#include <hip/hip_runtime.h>
#include <math.h>

// ---------------------------------------------------------------------------
// RefEncoder, MFMA edition.
// conv1: fp32 direct (Ci=3), NCHW in -> NHWC packed half2(hi, lo*4096) out.
// conv2/3/4: implicit-GEMM via v_mfma_f32_16x16x32_f16, fp16 2-term split:
//   x = hi + lo/4096;  C = A_hi*B_hi  (main acc)
//   Ccross = A_hi*B_lo' + A_lo'*B_hi  (lo' = lo*4096, scaled to stay normal)
//   result = C + Ccross/4096          (dropped term ~2^-24 rel: fp32-class)
// Verified layouts (learn_hip m89/m120): A[m=lane&15][k=(lane>>4)*8+j],
// B[n=lane&15][k=(lane>>4)*8+j], C/D: col(N)=lane&15, row(M)=(lane>>4)*4+reg.
// M = out pixels (m-tile = one oy row of 16 ox), N = co, K = ci per tap (x9).
// A window in LDS (pitch 40 halfs -> b128 at 32-bank floor), B pre-swizzled
// to fragment order by prep kernels, staged 8KB/tap to LDS.
// conv4 emits fp32 NHWC latent; head/kproj as before (argmax codes + [256,256]).
// ---------------------------------------------------------------------------

typedef _Float16 half8 __attribute__((ext_vector_type(8)));
typedef float floatx4 __attribute__((ext_vector_type(4)));
typedef unsigned int u32;
typedef unsigned short u16;

__device__ __forceinline__ float gelu_tanh(float x) {
    float x3 = x * x * x;
    return 0.5f * x * (1.0f + tanhf(0.7978845608028654f * (x + 0.044715f * x3)));
}

__device__ __forceinline__ u32 pack_split(float v) {
    _Float16 h = (_Float16)v;
    _Float16 l = (_Float16)((v - (float)h) * 4096.0f);
    union { _Float16 f; u16 s; } a, b;
    a.f = h; b.f = l;
    return (u32)a.s | ((u32)b.s << 16);
}

// ---- weight prep: OIHW fp32 -> B-fragment-ordered fp16 hi/lo planes -------
template <int Ci, int Co>
__global__ void prep_w(const float* __restrict__ W, _Float16* __restrict__ dH,
                       _Float16* __restrict__ dL) {
    constexpr int KC = Ci / 32, NTg = Co / 16;
    int lin = blockIdx.x * 256 + threadIdx.x;
    if (lin >= 9 * KC * NTg * 64) return;
    int l = lin & 63;
    int q = lin >> 6;
    int nt = q % NTg; q /= NTg;
    int kc = q % KC;
    int tap = q / KC;
    int co = nt * 16 + (l & 15);
    int ci0 = kc * 32 + ((l >> 4) << 3);
#pragma unroll
    for (int j = 0; j < 8; ++j) {
        float v = W[((size_t)co * Ci + ci0 + j) * 9 + tap];
        _Float16 h = (_Float16)v;
        _Float16 lo = (_Float16)((v - (float)h) * 4096.0f);
        dH[(size_t)lin * 8 + j] = h;
        dL[(size_t)lin * 8 + j] = lo;
    }
}

// ---- conv1: 3->64, fp32 direct, emits packed NHWC ------------------------
__launch_bounds__(256)
__global__ void conv1_k(const float* __restrict__ x, const float* __restrict__ w,
                        const float* __restrict__ bias, u32* __restrict__ out) {
    __shared__ float win[3 * 33 * 130];
    __shared__ float wsh[27 * 32];
    const int t = threadIdx.x;
    const int oyl = t >> 4, oxq = t & 15;
    int bx = blockIdx.x;
    const int cg = bx & 1;  bx >>= 1;
    const int oxt = bx & 1; bx >>= 1;
    const int oyt = bx & 7; bx >>= 3;
    const int n = bx;
    const int co0 = cg * 32;
    const int iy0 = oyt * 32, ix0 = oxt * 128;

    for (int e = t; e < 3 * 33 * 130; e += 256) {
        int ci = e / (33 * 130);
        int rem = e - ci * (33 * 130);
        int r = rem / 130, c = rem - r * 130;
        int iy = iy0 + r, ix = ix0 + c;
        float v = 0.0f;
        if (c < 129 && iy < 256 && ix < 256)
            v = 2.0f * x[((size_t)(n * 3 + ci) * 256 + iy) * 256 + ix] - 1.0f;
        win[e] = v;
    }
    for (int e = t; e < 864; e += 256) {
        int co = e & 31, ct = e >> 5;  // ct = ci*9+tap
        wsh[e] = w[(size_t)(co0 + co) * 27 + ct];
    }
    __syncthreads();

    float acc[32][4];
#pragma unroll
    for (int co = 0; co < 32; ++co)
#pragma unroll
        for (int p = 0; p < 4; ++p) acc[co][p] = 0.0f;

#pragma unroll
    for (int ci = 0; ci < 3; ++ci)
#pragma unroll
        for (int ky = 0; ky < 3; ++ky)
#pragma unroll
            for (int kx = 0; kx < 3; ++kx) {
                const float* wr = &win[(ci * 33 + 2 * oyl + ky) * 130 + 8 * oxq + kx];
                float v0 = wr[0], v1 = wr[2], v2 = wr[4], v3 = wr[6];
                const float* wp = &wsh[(ci * 9 + ky * 3 + kx) * 32];
#pragma unroll
                for (int co = 0; co < 32; ++co) {
                    float wv = wp[co];
                    acc[co][0] += v0 * wv; acc[co][1] += v1 * wv;
                    acc[co][2] += v2 * wv; acc[co][3] += v3 * wv;
                }
            }

    const int oy = oyt * 16 + oyl;
#pragma unroll
    for (int p = 0; p < 4; ++p) {
        int ox = oxt * 64 + 4 * oxq + p;
        size_t base = ((size_t)(n * 128 + oy) * 128 + ox) * 64 + co0;
#pragma unroll
        for (int cq = 0; cq < 8; ++cq) {
            uint4 st;
            st.x = pack_split(gelu_tanh(acc[4 * cq + 0][p] + bias[co0 + 4 * cq + 0]));
            st.y = pack_split(gelu_tanh(acc[4 * cq + 1][p] + bias[co0 + 4 * cq + 1]));
            st.z = pack_split(gelu_tanh(acc[4 * cq + 2][p] + bias[co0 + 4 * cq + 2]));
            st.w = pack_split(gelu_tanh(acc[4 * cq + 3][p] + bias[co0 + 4 * cq + 3]));
            *(uint4*)&out[base + 4 * cq] = st;
        }
    }
}

// ---- MFMA conv: stride-2 3x3, NHWC packed-half2 in, half2 or fp32 out ----
template <int Ci, int Co, int Hi, int Wi, bool GELU, bool SPLIT>
__launch_bounds__(512)
__global__ void conv_mfma(const u32* __restrict__ in, const _Float16* __restrict__ WbH,
                          const _Float16* __restrict__ WbL, const float* __restrict__ bias,
                          void* __restrict__ outp) {
    constexpr int Ho = Hi / 2, Wo = Wi / 2;
    constexpr int KC = Ci / 32, NTg = Co / 16;
    constexpr int OYT = Ho / 4, OXT = Wo / 16, CGT = Co / 128;
    constexpr int WC = 33, CIBP = 40;
    __shared__ _Float16 AH[9 * WC * CIBP], AL[9 * WC * CIBP];  // 2 x 23.76 KB
    __shared__ _Float16 BH[8 * 512], BL[8 * 512];              // 2 x 8 KB

    const int t = threadIdx.x, l = t & 63, wid = t >> 6;
    const int wm = wid >> 2, wn = wid & 3;  // wave grid 2(m) x 4(n)
    int bx = blockIdx.x;
    const int cg = bx % CGT;  bx /= CGT;
    const int oxt = bx % OXT; bx /= OXT;
    const int oyt = bx % OYT; bx /= OYT;
    const int n = bx;
    const int oy0 = oyt * 4, ox0 = oxt * 16, co0 = cg * 128, nt0 = co0 >> 4;
    const int iy0 = oy0 * 2, ix0 = ox0 * 2;

    floatx4 aM[2][2], aX[2][2];
    floatx4 zz = {0.0f, 0.0f, 0.0f, 0.0f};
#pragma unroll
    for (int a = 0; a < 2; ++a)
#pragma unroll
        for (int b = 0; b < 2; ++b) { aM[a][b] = zz; aX[a][b] = zz; }

    for (int kc = 0; kc < KC; ++kc) {
        __syncthreads();
        // stage A window slice: 9x33 px, 32 ci (8-ci groups), unpack hi/lo planes
        for (int e = t; e < 9 * WC * 4; e += 512) {
            int og = e & 3, px = e >> 2;
            int r = px / WC, cx = px - r * WC;
            int iy = iy0 + r, ix = ix0 + cx;
            union { float4 f4[2]; u32 u[8]; } buf;
            if (iy < Hi && ix < Wi) {
                const float4* g = (const float4*)(in + (((size_t)(n * Hi + iy) * Wi + ix) * Ci + kc * 32 + og * 8));
                buf.f4[0] = g[0]; buf.f4[1] = g[1];
            } else {
#pragma unroll
                for (int k2 = 0; k2 < 8; ++k2) buf.u[k2] = 0;
            }
            union { float4 f4; u16 s[8]; } hh, ll;
#pragma unroll
            for (int k2 = 0; k2 < 8; ++k2) {
                hh.s[k2] = (u16)buf.u[k2];
                ll.s[k2] = (u16)(buf.u[k2] >> 16);
            }
            int off = px * CIBP + og * 8;
            *(float4*)&AH[off] = hh.f4;
            *(float4*)&AL[off] = ll.f4;
        }
        for (int tap = 0; tap < 9; ++tap) {
            __syncthreads();
            {   // stage B fragments for this (tap, kc): 8 co-tiles x 512 halfs x 2 planes
                const size_t src = ((size_t)(tap * KC + kc) * NTg + nt0) * 512 + t * 8;
                *(float4*)&BH[t * 8] = *(const float4*)&WbH[src];
                *(float4*)&BL[t * 8] = *(const float4*)&WbL[src];
            }
            __syncthreads();
            const int ky = tap / 3, kx = tap - ky * 3;
            half8 bh[2], bl[2];
#pragma unroll
            for (int b = 0; b < 2; ++b) {
                int nt = wn * 2 + b;
                bh[b] = *(half8*)&BH[nt * 512 + l * 8];
                bl[b] = *(half8*)&BL[nt * 512 + l * 8];
            }
#pragma unroll
            for (int a = 0; a < 2; ++a) {
                int mt = wm * 2 + a;
                int off = ((2 * mt + ky) * WC + 2 * (l & 15) + kx) * CIBP + (l >> 4) * 8;
                half8 ah = *(half8*)&AH[off];
                half8 al = *(half8*)&AL[off];
#pragma unroll
                for (int b = 0; b < 2; ++b) {
                    aM[a][b] = __builtin_amdgcn_mfma_f32_16x16x32_f16(ah, bh[b], aM[a][b], 0, 0, 0);
                    aX[a][b] = __builtin_amdgcn_mfma_f32_16x16x32_f16(ah, bl[b], aX[a][b], 0, 0, 0);
                    aX[a][b] = __builtin_amdgcn_mfma_f32_16x16x32_f16(al, bh[b], aX[a][b], 0, 0, 0);
                }
            }
        }
    }

#pragma unroll
    for (int a = 0; a < 2; ++a) {
        int oy = oy0 + wm * 2 + a;
#pragma unroll
        for (int b = 0; b < 2; ++b) {
            int co = co0 + (wn * 2 + b) * 16 + (l & 15);
            float bj = bias[co];
#pragma unroll
            for (int r = 0; r < 4; ++r) {
                int ox = ox0 + (l >> 4) * 4 + r;
                float v = aM[a][b][r] + aX[a][b][r] * (1.0f / 4096.0f) + bj;
                if (GELU) v = gelu_tanh(v);
                size_t oidx = ((size_t)(n * Ho + oy) * Wo + ox) * Co + co;
                if (SPLIT) ((u32*)outp)[oidx] = pack_split(v);
                else       ((float*)outp)[oidx] = v;
            }
        }
    }
}

// ---- kproj / head (fp32 exact) -------------------------------------------
__global__ void kproj_kernel(const float* __restrict__ cb,
                             const float* __restrict__ wk,
                             float* __restrict__ kp) {
    int m = blockIdx.x >> 8;
    int k = blockIdx.x & 255;
    int c = threadIdx.x;
    const float* cbp = cb + (size_t)(m * 256 + k) * 64;
    const float* wkp = wk + (size_t)(m * 64 + c) * 64;
    float acc = 0.0f;
#pragma unroll 8
    for (int d = 0; d < 64; ++d) acc += cbp[d] * wkp[d];
    kp[(size_t)(m * 256 + k) * 64 + c] = acc;
}

__global__ void head_kernel(const float* __restrict__ latent,  // NHWC fp32
                            const float* __restrict__ wq,
                            const float* __restrict__ kp,
                            int* __restrict__ out) {
    __shared__ float lat[256];
    __shared__ float q[256];
    int t = threadIdx.x;
    int pix = blockIdx.x;
    lat[t] = latent[(size_t)pix * 256 + t];
    __syncthreads();

    int m = t >> 6, c = t & 63;
    const float* wqp = wq + (size_t)(m * 64 + c) * 64;
    float acc = 0.0f;
#pragma unroll 8
    for (int d = 0; d < 64; ++d) acc += lat[m * 64 + d] * wqp[d];
    q[t] = acc;
    __syncthreads();

    float best = -INFINITY;
    int bestk = 0;
    for (int j = 0; j < 4; ++j) {
        int k = j * 64 + c;
        const float* kpp = kp + (size_t)(m * 256 + k) * 64;
        float s = 0.0f;
#pragma unroll 8
        for (int d = 0; d < 64; ++d) s += q[m * 64 + d] * kpp[d];
        if (s > best) { best = s; bestk = k; }
    }
    for (int off = 32; off > 0; off >>= 1) {
        float s2 = __shfl_down(best, off, 64);
        int   k2 = __shfl_down(bestk, off, 64);
        if (s2 > best || (s2 == best && k2 < bestk)) { best = s2; bestk = k2; }
    }
    if (c == 0) out[pix * 4 + m] = bestk;
    if (pix == 0 && t == 0) { out[16384] = 256; out[16385] = 256; }
}

extern "C" void kernel_launch(void* const* d_in, const int* in_sizes, int n_in,
                              void* d_out, int out_size, void* d_ws, size_t ws_size,
                              hipStream_t stream) {
    const float* x  = (const float*)d_in[0];
    const float* w1 = (const float*)d_in[1];  const float* b1 = (const float*)d_in[2];
    const float* w2 = (const float*)d_in[3];  const float* b2 = (const float*)d_in[4];
    const float* w3 = (const float*)d_in[5];  const float* b3 = (const float*)d_in[6];
    const float* w4 = (const float*)d_in[7];  const float* b4 = (const float*)d_in[8];
    const float* cb = (const float*)d_in[9];
    const float* wq = (const float*)d_in[10];
    const float* wk = (const float*)d_in[11];
    int* out = (int*)d_out;

    char* ws = (char*)d_ws;
    u32*   buf1 = (u32*)ws;                         // 16*128*128*64 u32 = 64 MiB
    u32*   buf2 = (u32*)(ws + 67108864);            // 16*64*64*128  u32 = 32 MiB
    u32*   buf3 = (u32*)(ws + 100663296);           // 16*32*32*256  u32 = 16 MiB
    float* buf4 = (float*)(ws + 117440512);         // 16*16*16*256  f32 =  4 MiB
    float* kp   = (float*)(ws + 121634816);         // 4*256*64

    // Wb aliasing into dead regions (launch order makes this safe):
    _Float16* w2H = (_Float16*)(ws + 100663296);    // in buf3 (dead until conv3)
    _Float16* w2L = w2H + 9 * 2 * 8 * 512;
    _Float16* w3H = (_Float16*)ws;                  // in buf1 (dead after conv2)
    _Float16* w3L = w3H + 9 * 4 * 16 * 512;
    _Float16* w4H = w3L + 9 * 4 * 16 * 512;
    _Float16* w4L = w4H + 9 * 8 * 16 * 512;

    prep_w<64, 128><<<36, 256, 0, stream>>>(w2, w2H, w2L);
    conv1_k<<<512, 256, 0, stream>>>(x, w1, b1, buf1);
    conv_mfma<64, 128, 128, 128, true, true><<<1024, 512, 0, stream>>>(buf1, w2H, w2L, b2, buf2);
    prep_w<128, 256><<<144, 256, 0, stream>>>(w3, w3H, w3L);
    prep_w<256, 256><<<288, 256, 0, stream>>>(w4, w4H, w4L);
    conv_mfma<128, 256, 64, 64, true, true><<<512, 512, 0, stream>>>(buf2, w3H, w3L, b3, buf3);
    conv_mfma<256, 256, 32, 32, false, false><<<128, 512, 0, stream>>>(buf3, w4H, w4L, b4, buf4);
    kproj_kernel<<<4 * 256, 64, 0, stream>>>(cb, wk, kp);
    head_kernel<<<16 * 16 * 16, 256, 0, stream>>>(buf4, wq, kp, out);
}

// Round 7
// 462.564 us; speedup vs baseline: 4.6764x; 2.7299x over previous
//
#include <hip/hip_runtime.h>
#include <math.h>

// ---------------------------------------------------------------------------
// RefEncoder, MFMA edition (round 7: conv1 OOB staging guard fixed, c<256).
// conv1: fp32 direct, block 256 = tx16 x ty8 x cz2; tile 8 oy x 128 ox x 16 co;
//   acc[8co][8px] = 64 VGPRs, window 17x260 LDS restaged per ci, weights in
//   LDS broadcast. Emits NHWC packed half2(hi, lo*4096) u32.
// conv2/3/4: implicit-GEMM via v_mfma_f32_16x16x32_f16, fp16 2-term split:
//   x = hi + lo/4096;  C = A_hi*B_hi ; Ccross = A_hi*B_lo' + A_lo'*B_hi
//   result = C + Ccross/4096 (dropped al*bl ~2^-24 rel: fp32-class)
// Verified layouts (learn_hip m89/m120): A[m=lane&15][k=(lane>>4)*8+j],
// B[n=lane&15][k=(lane>>4)*8+j], C/D: col(N)=lane&15, row(M)=(lane>>4)*4+reg.
// conv4 emits fp32 NHWC latent; head computes q-proj, scores, argmax codes.
// Output (int32): 16384 codes [n,hh,ww,m] + tail [256,256]
// ---------------------------------------------------------------------------

typedef _Float16 half8 __attribute__((ext_vector_type(8)));
typedef float floatx4 __attribute__((ext_vector_type(4)));
typedef unsigned int u32;
typedef unsigned short u16;

__device__ __forceinline__ float gelu_tanh(float x) {
    float x3 = x * x * x;
    return 0.5f * x * (1.0f + tanhf(0.7978845608028654f * (x + 0.044715f * x3)));
}

__device__ __forceinline__ u32 pack_split(float v) {
    _Float16 h = (_Float16)v;
    _Float16 l = (_Float16)((v - (float)h) * 4096.0f);
    union { _Float16 f; u16 s; } a, b;
    a.f = h; b.f = l;
    return (u32)a.s | ((u32)b.s << 16);
}

// ---- weight prep: OIHW fp32 -> B-fragment-ordered fp16 hi/lo planes -------
template <int Ci, int Co>
__global__ void prep_w(const float* __restrict__ W, _Float16* __restrict__ dH,
                       _Float16* __restrict__ dL) {
    constexpr int KC = Ci / 32, NTg = Co / 16;
    int lin = blockIdx.x * 256 + threadIdx.x;
    if (lin >= 9 * KC * NTg * 64) return;
    int l = lin & 63;
    int q = lin >> 6;
    int nt = q % NTg; q /= NTg;
    int kc = q % KC;
    int tap = q / KC;
    int co = nt * 16 + (l & 15);
    int ci0 = kc * 32 + ((l >> 4) << 3);
#pragma unroll
    for (int j = 0; j < 8; ++j) {
        float v = W[((size_t)co * Ci + ci0 + j) * 9 + tap];
        _Float16 h = (_Float16)v;
        _Float16 lo = (_Float16)((v - (float)h) * 4096.0f);
        dH[(size_t)lin * 8 + j] = h;
        dL[(size_t)lin * 8 + j] = lo;
    }
}

// ---- conv1: 3->64, fp32 direct, low-VGPR tile, emits packed NHWC ---------
__launch_bounds__(256)
__global__ void conv1_k(const float* __restrict__ x, const float* __restrict__ w,
                        const float* __restrict__ bias, u32* __restrict__ out) {
    __shared__ float win[17 * 260];     // one ci slice, rows iy0..iy0+16
    __shared__ float wsh[27 * 64];      // [ci*9+tap][co]
    const int t = threadIdx.x;
    const int tx = t & 15, ty = (t >> 4) & 7, cz = t >> 7;
    int bx = blockIdx.x;
    const int cg = bx & 3;
    const int oyt = (bx >> 2) & 15;
    const int n = bx >> 6;
    const int co0 = cg * 16 + cz * 8;
    const int oy = oyt * 8 + ty;
    const int ox0 = tx * 8;
    const int iy0 = oyt * 16;

    for (int e = t; e < 27 * 64; e += 256) {
        int co = e & 63, ct = e >> 6;   // ct = ci*9+ky*3+kx
        wsh[ct * 64 + co] = w[co * 27 + ct];
    }

    float acc[8][8];
#pragma unroll
    for (int c = 0; c < 8; ++c)
#pragma unroll
        for (int p = 0; p < 8; ++p) acc[c][p] = 0.0f;

    for (int ci = 0; ci < 3; ++ci) {
        __syncthreads();
        for (int e = t; e < 17 * 260; e += 256) {
            int r = e / 260, c = e - r * 260;
            int iy = iy0 + r;
            float v = 0.0f;
            if (c < 256 && iy < 256)   // valid input cols 0..255; col>=256 is SAME pad -> 0
                v = 2.0f * x[((size_t)(n * 3 + ci) * 256 + iy) * 256 + c] - 1.0f;
            win[e] = v;
        }
        __syncthreads();

#pragma unroll
        for (int ky = 0; ky < 3; ++ky) {
            const float* rowp = &win[(2 * ty + ky) * 260 + 16 * tx];
            float rv[20];
#pragma unroll
            for (int q = 0; q < 5; ++q) {
                float4 v4 = *(const float4*)(rowp + 4 * q);
                rv[4 * q + 0] = v4.x; rv[4 * q + 1] = v4.y;
                rv[4 * q + 2] = v4.z; rv[4 * q + 3] = v4.w;
            }
#pragma unroll
            for (int kx = 0; kx < 3; ++kx) {
                const float* wp = &wsh[(ci * 9 + ky * 3 + kx) * 64 + co0];
                float wv[8];
#pragma unroll
                for (int q = 0; q < 2; ++q) {
                    float4 v4 = *(const float4*)(wp + 4 * q);  // broadcast
                    wv[4 * q + 0] = v4.x; wv[4 * q + 1] = v4.y;
                    wv[4 * q + 2] = v4.z; wv[4 * q + 3] = v4.w;
                }
#pragma unroll
                for (int c = 0; c < 8; ++c)
#pragma unroll
                    for (int p = 0; p < 8; ++p)
                        acc[c][p] += rv[2 * p + kx] * wv[c];
            }
        }
    }

    float bj[8];
#pragma unroll
    for (int c = 0; c < 8; ++c) bj[c] = bias[co0 + c];
#pragma unroll
    for (int p = 0; p < 8; ++p) {
        int ox = ox0 + p;
        size_t base = ((size_t)(n * 128 + oy) * 128 + ox) * 64 + co0;
        uint4 s0, s1;
        s0.x = pack_split(gelu_tanh(acc[0][p] + bj[0]));
        s0.y = pack_split(gelu_tanh(acc[1][p] + bj[1]));
        s0.z = pack_split(gelu_tanh(acc[2][p] + bj[2]));
        s0.w = pack_split(gelu_tanh(acc[3][p] + bj[3]));
        s1.x = pack_split(gelu_tanh(acc[4][p] + bj[4]));
        s1.y = pack_split(gelu_tanh(acc[5][p] + bj[5]));
        s1.z = pack_split(gelu_tanh(acc[6][p] + bj[6]));
        s1.w = pack_split(gelu_tanh(acc[7][p] + bj[7]));
        *(uint4*)&out[base] = s0;
        *(uint4*)&out[base + 4] = s1;
    }
}

// ---- MFMA conv: stride-2 3x3, NHWC packed-half2 in, half2 or fp32 out ----
template <int Ci, int Co, int Hi, int Wi, bool GELU, bool SPLIT>
__launch_bounds__(512)
__global__ void conv_mfma(const u32* __restrict__ in, const _Float16* __restrict__ WbH,
                          const _Float16* __restrict__ WbL, const float* __restrict__ bias,
                          void* __restrict__ outp) {
    constexpr int Ho = Hi / 2, Wo = Wi / 2;
    constexpr int KC = Ci / 32, NTg = Co / 16;
    constexpr int OYT = Ho / 4, OXT = Wo / 16, CGT = Co / 128;
    constexpr int WC = 33, CIBP = 40;
    __shared__ _Float16 AH[9 * WC * CIBP], AL[9 * WC * CIBP];
    __shared__ _Float16 BH[8 * 512], BL[8 * 512];

    const int t = threadIdx.x, l = t & 63, wid = t >> 6;
    const int wm = wid >> 2, wn = wid & 3;
    int bx = blockIdx.x;
    const int cg = bx % CGT;  bx /= CGT;
    const int oxt = bx % OXT; bx /= OXT;
    const int oyt = bx % OYT; bx /= OYT;
    const int n = bx;
    const int oy0 = oyt * 4, ox0 = oxt * 16, co0 = cg * 128, nt0 = co0 >> 4;
    const int iy0 = oy0 * 2, ix0 = ox0 * 2;

    floatx4 aM[2][2], aX[2][2];
    floatx4 zz = {0.0f, 0.0f, 0.0f, 0.0f};
#pragma unroll
    for (int a = 0; a < 2; ++a)
#pragma unroll
        for (int b = 0; b < 2; ++b) { aM[a][b] = zz; aX[a][b] = zz; }

    for (int kc = 0; kc < KC; ++kc) {
        __syncthreads();
        for (int e = t; e < 9 * WC * 4; e += 512) {
            int og = e & 3, px = e >> 2;
            int r = px / WC, cx = px - r * WC;
            int iy = iy0 + r, ix = ix0 + cx;
            union { float4 f4[2]; u32 u[8]; } buf;
            if (iy < Hi && ix < Wi) {
                const float4* g = (const float4*)(in + (((size_t)(n * Hi + iy) * Wi + ix) * Ci + kc * 32 + og * 8));
                buf.f4[0] = g[0]; buf.f4[1] = g[1];
            } else {
#pragma unroll
                for (int k2 = 0; k2 < 8; ++k2) buf.u[k2] = 0;
            }
            union { float4 f4; u16 s[8]; } hh, ll;
#pragma unroll
            for (int k2 = 0; k2 < 8; ++k2) {
                hh.s[k2] = (u16)buf.u[k2];
                ll.s[k2] = (u16)(buf.u[k2] >> 16);
            }
            int off = px * CIBP + og * 8;
            *(float4*)&AH[off] = hh.f4;
            *(float4*)&AL[off] = ll.f4;
        }
        for (int tap = 0; tap < 9; ++tap) {
            __syncthreads();
            {
                const size_t src = ((size_t)(tap * KC + kc) * NTg + nt0) * 512 + t * 8;
                *(float4*)&BH[t * 8] = *(const float4*)&WbH[src];
                *(float4*)&BL[t * 8] = *(const float4*)&WbL[src];
            }
            __syncthreads();
            const int ky = tap / 3, kx = tap - ky * 3;
            half8 bh[2], bl[2];
#pragma unroll
            for (int b = 0; b < 2; ++b) {
                int nt = wn * 2 + b;
                bh[b] = *(half8*)&BH[nt * 512 + l * 8];
                bl[b] = *(half8*)&BL[nt * 512 + l * 8];
            }
#pragma unroll
            for (int a = 0; a < 2; ++a) {
                int mt = wm * 2 + a;
                int off = ((2 * mt + ky) * WC + 2 * (l & 15) + kx) * CIBP + (l >> 4) * 8;
                half8 ah = *(half8*)&AH[off];
                half8 al = *(half8*)&AL[off];
#pragma unroll
                for (int b = 0; b < 2; ++b) {
                    aM[a][b] = __builtin_amdgcn_mfma_f32_16x16x32_f16(ah, bh[b], aM[a][b], 0, 0, 0);
                    aX[a][b] = __builtin_amdgcn_mfma_f32_16x16x32_f16(ah, bl[b], aX[a][b], 0, 0, 0);
                    aX[a][b] = __builtin_amdgcn_mfma_f32_16x16x32_f16(al, bh[b], aX[a][b], 0, 0, 0);
                }
            }
        }
    }

#pragma unroll
    for (int a = 0; a < 2; ++a) {
        int oy = oy0 + wm * 2 + a;
#pragma unroll
        for (int b = 0; b < 2; ++b) {
            int co = co0 + (wn * 2 + b) * 16 + (l & 15);
            float bj = bias[co];
#pragma unroll
            for (int r = 0; r < 4; ++r) {
                int ox = ox0 + (l >> 4) * 4 + r;
                float v = aM[a][b][r] + aX[a][b][r] * (1.0f / 4096.0f) + bj;
                if (GELU) v = gelu_tanh(v);
                size_t oidx = ((size_t)(n * Ho + oy) * Wo + ox) * Co + co;
                if (SPLIT) ((u32*)outp)[oidx] = pack_split(v);
                else       ((float*)outp)[oidx] = v;
            }
        }
    }
}

// ---- kproj / head (fp32 exact) -------------------------------------------
__global__ void kproj_kernel(const float* __restrict__ cb,
                             const float* __restrict__ wk,
                             float* __restrict__ kp) {
    int m = blockIdx.x >> 8;
    int k = blockIdx.x & 255;
    int c = threadIdx.x;
    const float* cbp = cb + (size_t)(m * 256 + k) * 64;
    const float* wkp = wk + (size_t)(m * 64 + c) * 64;
    float acc = 0.0f;
#pragma unroll 8
    for (int d = 0; d < 64; ++d) acc += cbp[d] * wkp[d];
    kp[(size_t)(m * 256 + k) * 64 + c] = acc;
}

__global__ void head_kernel(const float* __restrict__ latent,  // NHWC fp32
                            const float* __restrict__ wq,
                            const float* __restrict__ kp,
                            int* __restrict__ out) {
    __shared__ float lat[256];
    __shared__ float q[256];
    int t = threadIdx.x;
    int pix = blockIdx.x;
    lat[t] = latent[(size_t)pix * 256 + t];
    __syncthreads();

    int m = t >> 6, c = t & 63;
    const float* wqp = wq + (size_t)(m * 64 + c) * 64;
    float acc = 0.0f;
#pragma unroll 8
    for (int d = 0; d < 64; ++d) acc += lat[m * 64 + d] * wqp[d];
    q[t] = acc;
    __syncthreads();

    float best = -INFINITY;
    int bestk = 0;
    for (int j = 0; j < 4; ++j) {
        int k = j * 64 + c;
        const float* kpp = kp + (size_t)(m * 256 + k) * 64;
        float s = 0.0f;
#pragma unroll 8
        for (int d = 0; d < 64; ++d) s += q[m * 64 + d] * kpp[d];
        if (s > best) { best = s; bestk = k; }
    }
    for (int off = 32; off > 0; off >>= 1) {
        float s2 = __shfl_down(best, off, 64);
        int   k2 = __shfl_down(bestk, off, 64);
        if (s2 > best || (s2 == best && k2 < bestk)) { best = s2; bestk = k2; }
    }
    if (c == 0) out[pix * 4 + m] = bestk;
    if (pix == 0 && t == 0) { out[16384] = 256; out[16385] = 256; }
}

extern "C" void kernel_launch(void* const* d_in, const int* in_sizes, int n_in,
                              void* d_out, int out_size, void* d_ws, size_t ws_size,
                              hipStream_t stream) {
    const float* x  = (const float*)d_in[0];
    const float* w1 = (const float*)d_in[1];  const float* b1 = (const float*)d_in[2];
    const float* w2 = (const float*)d_in[3];  const float* b2 = (const float*)d_in[4];
    const float* w3 = (const float*)d_in[5];  const float* b3 = (const float*)d_in[6];
    const float* w4 = (const float*)d_in[7];  const float* b4 = (const float*)d_in[8];
    const float* cb = (const float*)d_in[9];
    const float* wq = (const float*)d_in[10];
    const float* wk = (const float*)d_in[11];
    int* out = (int*)d_out;

    char* ws = (char*)d_ws;
    u32*   buf1 = (u32*)ws;                         // 16*128*128*64 u32 = 64 MiB
    u32*   buf2 = (u32*)(ws + 67108864);            // 16*64*64*128  u32 = 32 MiB
    u32*   buf3 = (u32*)(ws + 100663296);           // 16*32*32*256  u32 = 16 MiB
    float* buf4 = (float*)(ws + 117440512);         // 16*16*16*256  f32 =  4 MiB
    float* kp   = (float*)(ws + 121634816);         // 4*256*64

    _Float16* w2H = (_Float16*)(ws + 100663296);    // in buf3 (dead until conv3)
    _Float16* w2L = w2H + 9 * 2 * 8 * 512;
    _Float16* w3H = (_Float16*)ws;                  // in buf1 (dead after conv2)
    _Float16* w3L = w3H + 9 * 4 * 16 * 512;
    _Float16* w4H = w3L + 9 * 4 * 16 * 512;
    _Float16* w4L = w4H + 9 * 8 * 16 * 512;

    prep_w<64, 128><<<36, 256, 0, stream>>>(w2, w2H, w2L);
    conv1_k<<<1024, 256, 0, stream>>>(x, w1, b1, buf1);
    conv_mfma<64, 128, 128, 128, true, true><<<1024, 512, 0, stream>>>(buf1, w2H, w2L, b2, buf2);
    prep_w<128, 256><<<144, 256, 0, stream>>>(w3, w3H, w3L);
    prep_w<256, 256><<<288, 256, 0, stream>>>(w4, w4H, w4L);
    conv_mfma<128, 256, 64, 64, true, true><<<512, 512, 0, stream>>>(buf2, w3H, w3L, b3, buf3);
    conv_mfma<256, 256, 32, 32, false, false><<<128, 512, 0, stream>>>(buf3, w4H, w4L, b4, buf4);
    kproj_kernel<<<4 * 256, 64, 0, stream>>>(cb, wk, kp);
    head_kernel<<<16 * 16 * 16, 256, 0, stream>>>(buf4, wq, kp, out);
}

// Round 8
// 357.280 us; speedup vs baseline: 6.0544x; 1.2947x over previous
//
#include <hip/hip_runtime.h>
#include <math.h>

// ---------------------------------------------------------------------------
// RefEncoder, MFMA edition (round 8: head collapsed to lat·M, M precomputed).
// conv1: fp32 direct, low-VGPR tile, emits NHWC packed half2(hi, lo*4096).
// conv2/3/4: implicit-GEMM via v_mfma_f32_16x16x32_f16, fp16 2-term split:
//   x = hi + lo/4096;  C = A_hi*B_hi ; Ccross = A_hi*B_lo' + A_lo'*B_hi
//   result = C + Ccross/4096 (dropped al*bl ~2^-24 rel: fp32-class)
// head: scores[px,m,k] = sum_d latent[px,m*64+d] * M[m,k,d] where
//   M[m][k][d] = sum_c wq[m][c][d] * kproj[m][k][c];  kproj from codebook/wk.
//   Eliminates per-pixel q-proj and all uncoalesced gathers.
// Output (int32): 16384 codes [n,hh,ww,m] + tail [256,256]
// ---------------------------------------------------------------------------

typedef _Float16 half8 __attribute__((ext_vector_type(8)));
typedef float floatx4 __attribute__((ext_vector_type(4)));
typedef unsigned int u32;
typedef unsigned short u16;

__device__ __forceinline__ float gelu_tanh(float x) {
    float x3 = x * x * x;
    return 0.5f * x * (1.0f + tanhf(0.7978845608028654f * (x + 0.044715f * x3)));
}

__device__ __forceinline__ u32 pack_split(float v) {
    _Float16 h = (_Float16)v;
    _Float16 l = (_Float16)((v - (float)h) * 4096.0f);
    union { _Float16 f; u16 s; } a, b;
    a.f = h; b.f = l;
    return (u32)a.s | ((u32)b.s << 16);
}

// ---- weight prep: OIHW fp32 -> B-fragment-ordered fp16 hi/lo planes -------
template <int Ci, int Co>
__global__ void prep_w(const float* __restrict__ W, _Float16* __restrict__ dH,
                       _Float16* __restrict__ dL) {
    constexpr int KC = Ci / 32, NTg = Co / 16;
    int lin = blockIdx.x * 256 + threadIdx.x;
    if (lin >= 9 * KC * NTg * 64) return;
    int l = lin & 63;
    int q = lin >> 6;
    int nt = q % NTg; q /= NTg;
    int kc = q % KC;
    int tap = q / KC;
    int co = nt * 16 + (l & 15);
    int ci0 = kc * 32 + ((l >> 4) << 3);
#pragma unroll
    for (int j = 0; j < 8; ++j) {
        float v = W[((size_t)co * Ci + ci0 + j) * 9 + tap];
        _Float16 h = (_Float16)v;
        _Float16 lo = (_Float16)((v - (float)h) * 4096.0f);
        dH[(size_t)lin * 8 + j] = h;
        dL[(size_t)lin * 8 + j] = lo;
    }
}

// ---- conv1: 3->64, fp32 direct, low-VGPR tile, emits packed NHWC ---------
__launch_bounds__(256)
__global__ void conv1_k(const float* __restrict__ x, const float* __restrict__ w,
                        const float* __restrict__ bias, u32* __restrict__ out) {
    __shared__ float win[17 * 260];     // one ci slice, rows iy0..iy0+16
    __shared__ float wsh[27 * 64];      // [ci*9+tap][co]
    const int t = threadIdx.x;
    const int tx = t & 15, ty = (t >> 4) & 7, cz = t >> 7;
    int bx = blockIdx.x;
    const int cg = bx & 3;
    const int oyt = (bx >> 2) & 15;
    const int n = bx >> 6;
    const int co0 = cg * 16 + cz * 8;
    const int oy = oyt * 8 + ty;
    const int ox0 = tx * 8;
    const int iy0 = oyt * 16;

    for (int e = t; e < 27 * 64; e += 256) {
        int co = e & 63, ct = e >> 6;   // ct = ci*9+ky*3+kx
        wsh[ct * 64 + co] = w[co * 27 + ct];
    }

    float acc[8][8];
#pragma unroll
    for (int c = 0; c < 8; ++c)
#pragma unroll
        for (int p = 0; p < 8; ++p) acc[c][p] = 0.0f;

    for (int ci = 0; ci < 3; ++ci) {
        __syncthreads();
        for (int e = t; e < 17 * 260; e += 256) {
            int r = e / 260, c = e - r * 260;
            int iy = iy0 + r;
            float v = 0.0f;
            if (c < 256 && iy < 256)   // col>=256 is SAME pad -> 0
                v = 2.0f * x[((size_t)(n * 3 + ci) * 256 + iy) * 256 + c] - 1.0f;
            win[e] = v;
        }
        __syncthreads();

#pragma unroll
        for (int ky = 0; ky < 3; ++ky) {
            const float* rowp = &win[(2 * ty + ky) * 260 + 16 * tx];
            float rv[20];
#pragma unroll
            for (int q = 0; q < 5; ++q) {
                float4 v4 = *(const float4*)(rowp + 4 * q);
                rv[4 * q + 0] = v4.x; rv[4 * q + 1] = v4.y;
                rv[4 * q + 2] = v4.z; rv[4 * q + 3] = v4.w;
            }
#pragma unroll
            for (int kx = 0; kx < 3; ++kx) {
                const float* wp = &wsh[(ci * 9 + ky * 3 + kx) * 64 + co0];
                float wv[8];
#pragma unroll
                for (int q = 0; q < 2; ++q) {
                    float4 v4 = *(const float4*)(wp + 4 * q);  // broadcast
                    wv[4 * q + 0] = v4.x; wv[4 * q + 1] = v4.y;
                    wv[4 * q + 2] = v4.z; wv[4 * q + 3] = v4.w;
                }
#pragma unroll
                for (int c = 0; c < 8; ++c)
#pragma unroll
                    for (int p = 0; p < 8; ++p)
                        acc[c][p] += rv[2 * p + kx] * wv[c];
            }
        }
    }

    float bj[8];
#pragma unroll
    for (int c = 0; c < 8; ++c) bj[c] = bias[co0 + c];
#pragma unroll
    for (int p = 0; p < 8; ++p) {
        int ox = ox0 + p;
        size_t base = ((size_t)(n * 128 + oy) * 128 + ox) * 64 + co0;
        uint4 s0, s1;
        s0.x = pack_split(gelu_tanh(acc[0][p] + bj[0]));
        s0.y = pack_split(gelu_tanh(acc[1][p] + bj[1]));
        s0.z = pack_split(gelu_tanh(acc[2][p] + bj[2]));
        s0.w = pack_split(gelu_tanh(acc[3][p] + bj[3]));
        s1.x = pack_split(gelu_tanh(acc[4][p] + bj[4]));
        s1.y = pack_split(gelu_tanh(acc[5][p] + bj[5]));
        s1.z = pack_split(gelu_tanh(acc[6][p] + bj[6]));
        s1.w = pack_split(gelu_tanh(acc[7][p] + bj[7]));
        *(uint4*)&out[base] = s0;
        *(uint4*)&out[base + 4] = s1;
    }
}

// ---- MFMA conv: stride-2 3x3, NHWC packed-half2 in, half2 or fp32 out ----
template <int Ci, int Co, int Hi, int Wi, bool GELU, bool SPLIT>
__launch_bounds__(512)
__global__ void conv_mfma(const u32* __restrict__ in, const _Float16* __restrict__ WbH,
                          const _Float16* __restrict__ WbL, const float* __restrict__ bias,
                          void* __restrict__ outp) {
    constexpr int Ho = Hi / 2, Wo = Wi / 2;
    constexpr int KC = Ci / 32, NTg = Co / 16;
    constexpr int OYT = Ho / 4, OXT = Wo / 16, CGT = Co / 128;
    constexpr int WC = 33, CIBP = 40;
    __shared__ _Float16 AH[9 * WC * CIBP], AL[9 * WC * CIBP];
    __shared__ _Float16 BH[8 * 512], BL[8 * 512];

    const int t = threadIdx.x, l = t & 63, wid = t >> 6;
    const int wm = wid >> 2, wn = wid & 3;
    int bx = blockIdx.x;
    const int cg = bx % CGT;  bx /= CGT;
    const int oxt = bx % OXT; bx /= OXT;
    const int oyt = bx % OYT; bx /= OYT;
    const int n = bx;
    const int oy0 = oyt * 4, ox0 = oxt * 16, co0 = cg * 128, nt0 = co0 >> 4;
    const int iy0 = oy0 * 2, ix0 = ox0 * 2;

    floatx4 aM[2][2], aX[2][2];
    floatx4 zz = {0.0f, 0.0f, 0.0f, 0.0f};
#pragma unroll
    for (int a = 0; a < 2; ++a)
#pragma unroll
        for (int b = 0; b < 2; ++b) { aM[a][b] = zz; aX[a][b] = zz; }

    for (int kc = 0; kc < KC; ++kc) {
        __syncthreads();
        for (int e = t; e < 9 * WC * 4; e += 512) {
            int og = e & 3, px = e >> 2;
            int r = px / WC, cx = px - r * WC;
            int iy = iy0 + r, ix = ix0 + cx;
            union { float4 f4[2]; u32 u[8]; } buf;
            if (iy < Hi && ix < Wi) {
                const float4* g = (const float4*)(in + (((size_t)(n * Hi + iy) * Wi + ix) * Ci + kc * 32 + og * 8));
                buf.f4[0] = g[0]; buf.f4[1] = g[1];
            } else {
#pragma unroll
                for (int k2 = 0; k2 < 8; ++k2) buf.u[k2] = 0;
            }
            union { float4 f4; u16 s[8]; } hh, ll;
#pragma unroll
            for (int k2 = 0; k2 < 8; ++k2) {
                hh.s[k2] = (u16)buf.u[k2];
                ll.s[k2] = (u16)(buf.u[k2] >> 16);
            }
            int off = px * CIBP + og * 8;
            *(float4*)&AH[off] = hh.f4;
            *(float4*)&AL[off] = ll.f4;
        }
        for (int tap = 0; tap < 9; ++tap) {
            __syncthreads();
            {
                const size_t src = ((size_t)(tap * KC + kc) * NTg + nt0) * 512 + t * 8;
                *(float4*)&BH[t * 8] = *(const float4*)&WbH[src];
                *(float4*)&BL[t * 8] = *(const float4*)&WbL[src];
            }
            __syncthreads();
            const int ky = tap / 3, kx = tap - ky * 3;
            half8 bh[2], bl[2];
#pragma unroll
            for (int b = 0; b < 2; ++b) {
                int nt = wn * 2 + b;
                bh[b] = *(half8*)&BH[nt * 512 + l * 8];
                bl[b] = *(half8*)&BL[nt * 512 + l * 8];
            }
#pragma unroll
            for (int a = 0; a < 2; ++a) {
                int mt = wm * 2 + a;
                int off = ((2 * mt + ky) * WC + 2 * (l & 15) + kx) * CIBP + (l >> 4) * 8;
                half8 ah = *(half8*)&AH[off];
                half8 al = *(half8*)&AL[off];
#pragma unroll
                for (int b = 0; b < 2; ++b) {
                    aM[a][b] = __builtin_amdgcn_mfma_f32_16x16x32_f16(ah, bh[b], aM[a][b], 0, 0, 0);
                    aX[a][b] = __builtin_amdgcn_mfma_f32_16x16x32_f16(ah, bl[b], aX[a][b], 0, 0, 0);
                    aX[a][b] = __builtin_amdgcn_mfma_f32_16x16x32_f16(al, bh[b], aX[a][b], 0, 0, 0);
                }
            }
        }
    }

#pragma unroll
    for (int a = 0; a < 2; ++a) {
        int oy = oy0 + wm * 2 + a;
#pragma unroll
        for (int b = 0; b < 2; ++b) {
            int co = co0 + (wn * 2 + b) * 16 + (l & 15);
            float bj = bias[co];
#pragma unroll
            for (int r = 0; r < 4; ++r) {
                int ox = ox0 + (l >> 4) * 4 + r;
                float v = aM[a][b][r] + aX[a][b][r] * (1.0f / 4096.0f) + bj;
                if (GELU) v = gelu_tanh(v);
                size_t oidx = ((size_t)(n * Ho + oy) * Wo + ox) * Co + co;
                if (SPLIT) ((u32*)outp)[oidx] = pack_split(v);
                else       ((float*)outp)[oidx] = v;
            }
        }
    }
}

// ---- head precompute ------------------------------------------------------
// kproj[m][k][c] = sum_d codebook[m][k][d] * wk[m][c][d]
__global__ void kproj_kernel(const float* __restrict__ cb,
                             const float* __restrict__ wk,
                             float* __restrict__ kp) {
    int m = blockIdx.x >> 8;
    int k = blockIdx.x & 255;
    int c = threadIdx.x;
    const float* cbp = cb + (size_t)(m * 256 + k) * 64;
    const float* wkp = wk + (size_t)(m * 64 + c) * 64;
    float acc = 0.0f;
#pragma unroll 8
    for (int d = 0; d < 64; ++d) acc += cbp[d] * wkp[d];
    kp[(size_t)(m * 256 + k) * 64 + c] = acc;
}

// M[m][k][d] = sum_c wq[m][c][d] * kproj[m][k][c]
__global__ void m_kernel(const float* __restrict__ wq,
                         const float* __restrict__ kp,
                         float* __restrict__ M) {
    int m = blockIdx.x >> 8;
    int k = blockIdx.x & 255;
    int d = threadIdx.x;
    const float* kpp = &kp[(size_t)(m * 256 + k) * 64];
    const float* wqp = &wq[(size_t)m * 64 * 64 + d];   // wq[m][c][d], stride 64
    float acc = 0.0f;
#pragma unroll 8
    for (int c = 0; c < 64; ++c) acc += wqp[c * 64] * kpp[c];
    M[((size_t)(m * 256 + k)) * 64 + d] = acc;
}

// ---- head: scores = lat . M, argmax over k -------------------------------
// block: 16 px x 4 m x 4 kq; thread scans 64 codes with latent row in regs.
__launch_bounds__(256)
__global__ void head_kernel(const float* __restrict__ latent,  // NHWC fp32
                            const float* __restrict__ M,
                            int* __restrict__ out) {
    __shared__ float rs[256];
    __shared__ int rk[256];
    const int t = threadIdx.x;
    const int px = t & 15, m = (t >> 4) & 3, kq = t >> 6;
    const int pix = blockIdx.x * 16 + px;

    float4 lr[16];
    const float4* lp = (const float4*)&latent[(size_t)pix * 256 + m * 64];
#pragma unroll
    for (int d = 0; d < 16; ++d) lr[d] = lp[d];

    float best = -INFINITY;
    int bestk = 0;
    const float4* Mp = (const float4*)&M[(size_t)((m * 256 + kq * 64)) * 64];
    for (int kk = 0; kk < 64; ++kk) {
        float s0 = 0.0f, s1 = 0.0f, s2 = 0.0f, s3 = 0.0f;
#pragma unroll
        for (int d = 0; d < 16; ++d) {
            float4 mv = Mp[kk * 16 + d];
            s0 += lr[d].x * mv.x; s1 += lr[d].y * mv.y;
            s2 += lr[d].z * mv.z; s3 += lr[d].w * mv.w;
        }
        float s = (s0 + s1) + (s2 + s3);
        if (s > best) { best = s; bestk = kq * 64 + kk; }  // ascending k: strict >
    }
    rs[t] = best; rk[t] = bestk;
    __syncthreads();
    if (kq == 0) {
#pragma unroll
        for (int q = 1; q < 4; ++q) {
            float sv = rs[t + 64 * q];
            int kv = rk[t + 64 * q];
            if (sv > best || (sv == best && kv < bestk)) { best = sv; bestk = kv; }
        }
        out[pix * 4 + m] = bestk;
    }
    if (blockIdx.x == 0 && t == 0) { out[16384] = 256; out[16385] = 256; }
}

extern "C" void kernel_launch(void* const* d_in, const int* in_sizes, int n_in,
                              void* d_out, int out_size, void* d_ws, size_t ws_size,
                              hipStream_t stream) {
    const float* x  = (const float*)d_in[0];
    const float* w1 = (const float*)d_in[1];  const float* b1 = (const float*)d_in[2];
    const float* w2 = (const float*)d_in[3];  const float* b2 = (const float*)d_in[4];
    const float* w3 = (const float*)d_in[5];  const float* b3 = (const float*)d_in[6];
    const float* w4 = (const float*)d_in[7];  const float* b4 = (const float*)d_in[8];
    const float* cb = (const float*)d_in[9];
    const float* wq = (const float*)d_in[10];
    const float* wk = (const float*)d_in[11];
    int* out = (int*)d_out;

    char* ws = (char*)d_ws;
    u32*   buf1 = (u32*)ws;                         // 16*128*128*64 u32 = 64 MiB
    u32*   buf2 = (u32*)(ws + 67108864);            // 16*64*64*128  u32 = 32 MiB
    u32*   buf3 = (u32*)(ws + 100663296);           // 16*32*32*256  u32 = 16 MiB
    float* buf4 = (float*)(ws + 117440512);         // 16*16*16*256  f32 =  4 MiB
    float* kp   = (float*)(ws + 121634816);         // 4*256*64 = 256 KiB
    float* Mbuf = (float*)(ws + 121634816 + 262144);// 4*256*64 = 256 KiB

    _Float16* w2H = (_Float16*)(ws + 100663296);    // in buf3 (dead until conv3)
    _Float16* w2L = w2H + 9 * 2 * 8 * 512;
    _Float16* w3H = (_Float16*)ws;                  // in buf1 (dead after conv2)
    _Float16* w3L = w3H + 9 * 4 * 16 * 512;
    _Float16* w4H = w3L + 9 * 4 * 16 * 512;
    _Float16* w4L = w4H + 9 * 8 * 16 * 512;

    prep_w<64, 128><<<36, 256, 0, stream>>>(w2, w2H, w2L);
    conv1_k<<<1024, 256, 0, stream>>>(x, w1, b1, buf1);
    conv_mfma<64, 128, 128, 128, true, true><<<1024, 512, 0, stream>>>(buf1, w2H, w2L, b2, buf2);
    prep_w<128, 256><<<144, 256, 0, stream>>>(w3, w3H, w3L);
    prep_w<256, 256><<<288, 256, 0, stream>>>(w4, w4H, w4L);
    conv_mfma<128, 256, 64, 64, true, true><<<512, 512, 0, stream>>>(buf2, w3H, w3L, b3, buf3);
    kproj_kernel<<<4 * 256, 64, 0, stream>>>(cb, wk, kp);
    m_kernel<<<4 * 256, 64, 0, stream>>>(wq, kp, Mbuf);
    conv_mfma<256, 256, 32, 32, false, false><<<128, 512, 0, stream>>>(buf3, w4H, w4L, b4, buf4);
    head_kernel<<<256, 256, 0, stream>>>(buf4, Mbuf, out);
}